// Round 9
// baseline (219.646 us; speedup 1.0000x reference)
//
#include <hip/hip_runtime.h>
#include <cstdint>
#include <cstddef>

// MultiHeadAttention R9:
//   cast -> MFMA QKV GEMM (TRIPLE-buffered K-loop with MANUAL barriers
//   `s_waitcnt vmcnt(N); s_barrier` -- prefetch distance 2, never drains the
//   in-flight prefetch; Q/K swapped-MFMA direct stores; V via LDS transpose) ->
//   MFMA flash attention (triple-buffered K staging w/ manual barriers, V
//   B-frags DIRECT from L2-resident Vt, no-max softmax) -> MFMA out-proj.
// ws layout (bytes):
//   xb @0 [4096][1024] bf16 | wqb @8388608 [3072][1024] | wob @14680064 [1024][1024]
//   Qb @16777216, Kb @25165824: [2][16][2048][64] bf16 (Qb = Q*log2e)
//   Vt @33554432: [2][16][64][2048] bf16 (transposed)
//   CTX @41943040 [4096][1024] bf16
// MFMA 16x16x32_bf16 frags: A[m=lane&15][k=quad*8+i], B[n=lane&15][k=quad*8+i],
// C/D[row=quad*4+reg][col=lane&15]. Swapped operands -> D = C^T.

typedef __attribute__((ext_vector_type(8))) short bf16x8;
typedef __attribute__((ext_vector_type(4))) float f32x4;

#define LOG2E 1.44269504f

#define MFMA16(a, b, c) __builtin_amdgcn_mfma_f32_16x16x32_bf16((a), (b), (c), 0, 0, 0)

#define GLDS16(g, s)                                                        \
  __builtin_amdgcn_global_load_lds(                                         \
      (const __attribute__((address_space(1))) void*)(g),                   \
      (__attribute__((address_space(3))) void*)(s), 16, 0, 0)

// Manual barrier: wait until <= N vector-memory ops outstanding, then barrier.
// Bypasses __syncthreads' vmcnt(0) drain so staged prefetches stay in flight.
#define ASYNC_BAR(N) asm volatile("s_waitcnt vmcnt(" #N ")\n\ts_barrier" ::: "memory")

#if __has_builtin(__builtin_amdgcn_exp2f)
#define EXP2F(x) __builtin_amdgcn_exp2f(x)
#else
#define EXP2F(x) exp2f(x)
#endif

static __device__ __forceinline__ unsigned short f2bf(float f) {  // RNE
  unsigned int u = __builtin_bit_cast(unsigned int, f);
  u += 0x7FFFu + ((u >> 16) & 1u);
  return (unsigned short)(u >> 16);
}

// pack two fp32 -> two bf16 (round-nearest) in one u32: 2 add + 1 perm
static __device__ __forceinline__ unsigned int pk2bf(float a, float b) {
  const unsigned int ua = __builtin_bit_cast(unsigned int, a) + 0x8000u;
  const unsigned int ub = __builtin_bit_cast(unsigned int, b) + 0x8000u;
  return __builtin_amdgcn_perm(ub, ua, 0x07060302);
}

// ---------------------------------------------------------------------------
__global__ __launch_bounds__(256) void cast_bf16(const float* __restrict__ x,
                                                 const float* __restrict__ wq,
                                                 const float* __restrict__ wo,
                                                 unsigned short* __restrict__ xb,
                                                 unsigned short* __restrict__ wqb,
                                                 unsigned short* __restrict__ wob)
{
  const int id = blockIdx.x * 256 + threadIdx.x;
  const float* src;
  unsigned short* dst;
  int off;
  if (id < 1048576)               { src = x;  dst = xb;  off = id; }
  else if (id < 1048576 + 786432) { src = wq; dst = wqb; off = id - 1048576; }
  else                            { src = wo; dst = wob; off = id - (1048576 + 786432); }
  float4 v = ((const float4*)src)[off];
  ushort4 o;
  o.x = f2bf(v.x); o.y = f2bf(v.y); o.z = f2bf(v.z); o.w = f2bf(v.w);
  ((ushort4*)dst)[off] = o;
}

// ---------------------------------------------------------------------------
// MFMA GEMM, TRIPLE-buffered K-loop, manual barriers (prefetch distance 2).
// Stage = 4 GLDS16/wave -> steady-state 8 in flight; vmcnt(4) drains exactly
// the stage the coming compute consumes. C[m,n] = sum_k A[m,k]*B[n,k].
// MODE 1: part 0/1 (Q/K): swapped MFMA -> direct ushort4 stores (Q * log2e).
//         part 2 (V): normal -> LDS-transpose -> Vt.
// MODE 0: swapped -> float4 stores + float4 bias.
// ---------------------------------------------------------------------------
template <int MODE>
__global__ __launch_bounds__(256) void gemm_bt(const unsigned short* __restrict__ A,
                                               const unsigned short* __restrict__ B,
                                               const float* __restrict__ bias,
                                               float* __restrict__ OutF,
                                               unsigned short* __restrict__ Qb,
                                               unsigned short* __restrict__ Kb,
                                               unsigned short* __restrict__ Vt)
{
  __shared__ unsigned short pool[24576];   // 3 stages x (A 4096 | B 4096) shorts

  const int tid  = threadIdx.x;
  const int wave = tid >> 6, lane = tid & 63, quad = lane >> 4, cl = lane & 15;
  const int wm = wave >> 1, wn = wave & 1;
  const int m0 = blockIdx.y * 128, n0 = blockIdx.x * 128;
  const int sr = lane >> 2, sc = lane & 3;

  const int part = (MODE == 1) ? (n0 >> 10) : 0;     // 0=Q 1=K 2=V
  const bool swapped = (MODE == 0) || (part < 2);

  f32x4 acc[4][4];
  #pragma unroll
  for (int i = 0; i < 4; ++i)
    #pragma unroll
    for (int j = 0; j < 4; ++j)
      #pragma unroll
      for (int r = 0; r < 4; ++r) acc[i][j][r] = 0.f;

  const int scs = (sc ^ ((sr >> 1) & 3)) * 8;
  const int rchunk = (quad ^ ((cl >> 1) & 3)) * 8;

  auto stage = [&](int k0, int buf) {
    unsigned short* As = pool + buf * 8192;
    unsigned short* Bs = As + 4096;
    #pragma unroll
    for (int ii = 0; ii < 2; ++ii) {
      const int r = wave * 32 + ii * 16 + sr;
      GLDS16(A + (size_t)(m0 + r) * 1024 + k0 + scs, &As[(wave * 32 + ii * 16) * 32]);
      GLDS16(B + (size_t)(n0 + r) * 1024 + k0 + scs, &Bs[(wave * 32 + ii * 16) * 32]);
    }
  };

  stage(0, 0);
  stage(32, 1);
  int cur = 0;
  #pragma unroll 1
  for (int it = 0; it < 32; ++it) {
    if (it + 2 < 32) {
      ASYNC_BAR(4);                              // drain stage(it); keep stage(it+1)
      const int bnx = (cur == 0) ? 2 : cur - 1;  // (cur+2)%3
      stage((it + 2) * 32, bnx);
    } else if (it + 1 < 32) {
      ASYNC_BAR(4);                              // 8 outstanding -> drain stage(it)
    } else {
      ASYNC_BAR(0);                              // last stage
    }

    const unsigned short* As = pool + cur * 8192;
    const unsigned short* Bs = As + 4096;
    bf16x8 af[4], bfr[4];
    #pragma unroll
    for (int mt = 0; mt < 4; ++mt)
      af[mt] = *(const bf16x8*)&As[(wm * 64 + mt * 16 + cl) * 32 + rchunk];
    #pragma unroll
    for (int nt = 0; nt < 4; ++nt)
      bfr[nt] = *(const bf16x8*)&Bs[(wn * 64 + nt * 16 + cl) * 32 + rchunk];

    if (swapped) {
      #pragma unroll
      for (int mt = 0; mt < 4; ++mt)
        #pragma unroll
        for (int nt = 0; nt < 4; ++nt)
          acc[mt][nt] = MFMA16(bfr[nt], af[mt], acc[mt][nt]);   // D = C^T
    } else {
      #pragma unroll
      for (int mt = 0; mt < 4; ++mt)
        #pragma unroll
        for (int nt = 0; nt < 4; ++nt)
          acc[mt][nt] = MFMA16(af[mt], bfr[nt], acc[mt][nt]);
    }
    cur = (cur == 2) ? 0 : cur + 1;
  }

  if (MODE == 1) {
    const int bb = m0 >> 11, ss = m0 & 2047;
    if (part == 2) {
      // V (normal orientation): transpose through LDS, coalesced Vt row stores
      #pragma unroll
      for (int half = 0; half < 2; ++half) {
        __syncthreads();
        if (wn == half) {
          #pragma unroll
          for (int mt = 0; mt < 4; ++mt)
            #pragma unroll
            for (int nt = 0; nt < 4; ++nt) {
              const int nl = nt * 16 + cl;
              const int ml = wm * 64 + mt * 16 + quad * 4;
              ushort4 pk;
              pk.x = f2bf(acc[mt][nt][0]); pk.y = f2bf(acc[mt][nt][1]);
              pk.z = f2bf(acc[mt][nt][2]); pk.w = f2bf(acc[mt][nt][3]);
              *(ushort4*)&pool[nl * 136 + ml] = pk;
            }
        }
        __syncthreads();
        const int row = tid >> 2, q4 = tid & 3;
        const int nglob = n0 + half * 64 + row;
        const int hh = (nglob >> 6) & 15, d = nglob & 63;
        unsigned short* drow = Vt + ((size_t)(bb * 16 + hh) * 64 + d) * 2048 + ss;
        #pragma unroll
        for (int i = 0; i < 4; ++i) {
          const bf16x8 v = *(const bf16x8*)&pool[row * 136 + q4 * 32 + i * 8];
          *(bf16x8*)(drow + q4 * 32 + i * 8) = v;
        }
      }
    } else {
      // Q/K (swapped: D=C^T): lane holds 4 consecutive d for one s -> ushort4
      unsigned short* dst = (part == 0) ? Qb : Kb;
      const float sc2 = (part == 0) ? LOG2E : 1.0f;
      #pragma unroll
      for (int mt = 0; mt < 4; ++mt) {
        const int m = ss + wm * 64 + mt * 16 + cl;
        #pragma unroll
        for (int nt = 0; nt < 4; ++nt) {
          const int np = (n0 & 1023) + wn * 64 + nt * 16 + quad * 4;
          const int hh = np >> 6, d0 = np & 63;
          ushort4 pk;
          pk.x = f2bf(acc[mt][nt][0] * sc2);
          pk.y = f2bf(acc[mt][nt][1] * sc2);
          pk.z = f2bf(acc[mt][nt][2] * sc2);
          pk.w = f2bf(acc[mt][nt][3] * sc2);
          *(ushort4*)&dst[((size_t)(bb * 16 + hh) * 2048 + m) * 64 + d0] = pk;
        }
      }
    }
  } else {
    #pragma unroll
    for (int mt = 0; mt < 4; ++mt) {
      const int m = m0 + wm * 64 + mt * 16 + cl;
      #pragma unroll
      for (int nt = 0; nt < 4; ++nt) {
        const int n = n0 + wn * 64 + nt * 16 + quad * 4;
        const float4 bv = *(const float4*)(bias + n);
        float4 o;
        o.x = acc[mt][nt][0] + bv.x; o.y = acc[mt][nt][1] + bv.y;
        o.z = acc[mt][nt][2] + bv.z; o.w = acc[mt][nt][3] + bv.w;
        *(float4*)&OutF[(size_t)m * 1024 + n] = o;
      }
    }
  }
}

// ---------------------------------------------------------------------------
// Flash attention R9: uniform blocks (wave owns low group g and high 127-g).
// K staged in LDS, TRIPLE-buffered, manual barriers (distance 2, vmcnt(2)).
// V B-frags read DIRECT from global Vt (L2-resident, XCD-affine mapping),
// issued at step top, consumed after the softmax chain. No-max softmax
// P = 2^(q·k·log2e); P round-trips per-wave LDS (stride 40).
// ---------------------------------------------------------------------------
__global__ __launch_bounds__(256) void attn_mfma(const unsigned short* __restrict__ Qb,
                                                 const unsigned short* __restrict__ Kb,
                                                 const unsigned short* __restrict__ Vt,
                                                 unsigned short* __restrict__ CTX)
{
  __shared__ unsigned short Ksm[3][64 * 64];
  __shared__ unsigned short Psm[4][32 * 40];

  const int tid  = threadIdx.x;
  const int wave = tid >> 6, lane = tid & 63, quad = lane >> 4, cl = lane & 15;

  const int L  = blockIdx.x;
  const int bh = 4 * (L & 7) + ((L >> 3) & 3);    // XCD-affine: 4 bh per XCD
  const int b  = bh >> 4, h = bh & 15;
  const int p  = L >> 5;                          // 0..15
  const int g  = p * 4 + wave;                    // low group 0..63
  const int qlo = g * 16;
  const int qhi = (127 - g) * 16;
  const size_t base = (size_t)bh * (2048 * 64);
  const unsigned short* Vp = Vt + base;

  bf16x8 qf[2][2];
  #pragma unroll
  for (int dk = 0; dk < 2; ++dk) {
    qf[0][dk] = *(const bf16x8*)(Qb + base + (size_t)(qlo + cl) * 64 + dk * 32 + quad * 8);
    qf[1][dk] = *(const bf16x8*)(Qb + base + (size_t)(qhi + cl) * 64 + dk * 32 + quad * 8);
  }

  f32x4 oacc[2][4];
  #pragma unroll
  for (int mf = 0; mf < 2; ++mf)
    #pragma unroll
    for (int dt = 0; dt < 4; ++dt)
      #pragma unroll
      for (int r = 0; r < 4; ++r) oacc[mf][dt][r] = 0.f;
  float lr[2][4] = {};

  bf16x8 ones;
  #pragma unroll
  for (int k = 0; k < 8; ++k) ones[k] = (short)0x3F80;

  const int lrow  = lane >> 3;
  const int lslot = (lane & 7) ^ lrow;
  const int nch = 32 - p;

  auto stageK = [&](int j64, int buf) {
    #pragma unroll
    for (int ii = 0; ii < 2; ++ii) {
      const int r0 = wave * 16 + ii * 8;
      GLDS16(Kb + base + (size_t)(j64 + r0 + lrow) * 64 + lslot * 8, &Ksm[buf][r0 * 64]);
    }
  };

  stageK(0, 0);
  stageK(64, 1);
  int cur = 0;
  #pragma unroll 1
  for (int ch = 0; ch < nch; ++ch) {
    if (ch + 2 < nch) {
      ASYNC_BAR(2);                              // drain stage(ch); keep stage(ch+1)
      const int bnx = (cur == 0) ? 2 : cur - 1;
      stageK((ch + 2) * 64, bnx);
    } else if (ch + 1 < nch) {
      ASYNC_BAR(2);
    } else {
      ASYNC_BAR(0);
    }

    const int j64 = ch * 64;
    #pragma unroll
    for (int jli = 0; jli < 2; ++jli) {
      const int jg0 = j64 + jli * 32;
      if (jg0 > qhi + 15) continue;
      const bool lowAct = (jg0 <= qlo + 15);
      const int jl = jli * 32;

      // V B-frags direct from L2 (issued early, consumed after softmax chain)
      bf16x8 vf[4];
      #pragma unroll
      for (int dt = 0; dt < 4; ++dt)
        vf[dt] = *(const bf16x8*)(Vp + (size_t)(dt * 16 + cl) * 2048 + jg0 + quad * 8);

      bf16x8 kf[2][2];
      #pragma unroll
      for (int jf = 0; jf < 2; ++jf)
        #pragma unroll
        for (int dk = 0; dk < 2; ++dk) {
          const int jrow = jl + jf * 16 + cl;
          const int slot = (dk * 4 + quad) ^ (cl & 7);
          kf[jf][dk] = *(const bf16x8*)&Ksm[cur][jrow * 64 + slot * 8];
        }

      f32x4 st[2][2];
      #pragma unroll
      for (int jf = 0; jf < 2; ++jf)
        #pragma unroll
        for (int mf = 0; mf < 2; ++mf) {
          if (mf == 0 && !lowAct) continue;
          f32x4 z;
          #pragma unroll
          for (int r = 0; r < 4; ++r) z[r] = 0.f;
          z = MFMA16(kf[jf][0], qf[mf][0], z);
          st[jf][mf] = MFMA16(kf[jf][1], qf[mf][1], z);
        }

      #pragma unroll
      for (int mf = 0; mf < 2; ++mf) {
        if (mf == 0 && !lowAct) continue;
        const int qbase = mf ? qhi : qlo;
        const bool diag = (jg0 + 32 > qbase);
        #pragma unroll
        for (int jf = 0; jf < 2; ++jf) {
          float pv[4];
          if (diag) {
            const int qg = qbase + cl;
            #pragma unroll
            for (int r = 0; r < 4; ++r) {
              const int jg = jg0 + jf * 16 + quad * 4 + r;
              pv[r] = (jg <= qg) ? EXP2F(st[jf][mf][r]) : 0.f;
            }
          } else {
            #pragma unroll
            for (int r = 0; r < 4; ++r) pv[r] = EXP2F(st[jf][mf][r]);
          }
          uint2 w;
          w.x = pk2bf(pv[0], pv[1]);
          w.y = pk2bf(pv[2], pv[3]);
          *(uint2*)&Psm[wave][(mf * 16 + cl) * 40 + jf * 16 + quad * 4] = w;
        }
      }

      #pragma unroll
      for (int mf = 0; mf < 2; ++mf) {
        if (mf == 0 && !lowAct) continue;
        const bf16x8 pf = *(const bf16x8*)&Psm[wave][(mf * 16 + cl) * 40 + quad * 8];
        f32x4 z;
        #pragma unroll
        for (int r = 0; r < 4; ++r) z[r] = 0.f;
        const f32x4 ls = MFMA16(pf, ones, z);
        #pragma unroll
        for (int r = 0; r < 4; ++r) lr[mf][r] += ls[r];
        #pragma unroll
        for (int dt = 0; dt < 4; ++dt)
          oacc[mf][dt] = MFMA16(pf, vf[dt], oacc[mf][dt]);
      }
    }
    cur = (cur == 2) ? 0 : cur + 1;
  }

  #pragma unroll
  for (int mf = 0; mf < 2; ++mf) {
    const int qbase = mf ? qhi : qlo;
    float inv[4];
    #pragma unroll
    for (int r = 0; r < 4; ++r) inv[r] = 1.f / lr[mf][r];
    #pragma unroll
    for (int dt = 0; dt < 4; ++dt)
      #pragma unroll
      for (int r = 0; r < 4; ++r)
        CTX[(size_t)(b * 2048 + qbase + quad * 4 + r) * 1024 +
            h * 64 + dt * 16 + cl] = f2bf(oacc[mf][dt][r] * inv[r]);
  }
}

// ---------------------------------------------------------------------------
extern "C" void kernel_launch(void* const* d_in, const int* in_sizes, int n_in,
                              void* d_out, int out_size, void* d_ws, size_t ws_size,
                              hipStream_t stream)
{
  const float* x    = (const float*)d_in[0];
  const float* Wqkv = (const float*)d_in[1];
  const float* Wout = (const float*)d_in[2];
  const float* bout = (const float*)d_in[3];
  float* out = (float*)d_out;

  char* ws = (char*)d_ws;
  unsigned short* xb  = (unsigned short*)(ws);
  unsigned short* wqb = (unsigned short*)(ws + 8388608);
  unsigned short* wob = (unsigned short*)(ws + 14680064);
  unsigned short* Qb  = (unsigned short*)(ws + 16777216);
  unsigned short* Kb  = (unsigned short*)(ws + 25165824);
  unsigned short* Vt  = (unsigned short*)(ws + 33554432);
  unsigned short* CTX = (unsigned short*)(ws + 41943040);

  cast_bf16<<<dim3(8192), dim3(256), 0, stream>>>(x, Wqkv, Wout, xb, wqb, wob);

  // QKV projection: M=4096, N=3072, K=1024
  gemm_bt<1><<<dim3(24, 32), dim3(256), 0, stream>>>(xb, wqb, nullptr, nullptr, Qb, Kb, Vt);

  // Flash attention: 512 uniform blocks (XCD-affine bh), 4 waves each
  attn_mfma<<<dim3(512), dim3(256), 0, stream>>>(Qb, Kb, Vt, CTX);

  // Output projection: M=4096, N=1024, K=1024, + bias
  gemm_bt<0><<<dim3(8, 32), dim3(256), 0, stream>>>(CTX, wob, bout, out, nullptr, nullptr, nullptr);
}

// Round 10
// 196.547 us; speedup vs baseline: 1.1175x; 1.1175x over previous
//
#include <hip/hip_runtime.h>
#include <cstdint>
#include <cstddef>

// MultiHeadAttention R10:
//   cast -> MFMA QKV GEMM (R9: triple-buffered K-loop, manual vmcnt barriers,
//   swapped-MFMA Q/K stores, V via LDS transpose) ->
//   MFMA flash attention (R8 structure: K AND V staged via GLDS, now
//   triple-buffered with manual vmcnt(4) barriers -- loop vmem = staging only,
//   so the accounting is exact; no-max softmax) -> MFMA out-proj.
// ws layout (bytes):
//   xb @0 [4096][1024] bf16 | wqb @8388608 [3072][1024] | wob @14680064 [1024][1024]
//   Qb @16777216, Kb @25165824: [2][16][2048][64] bf16 (Qb = Q*log2e)
//   Vt @33554432: [2][16][64][2048] bf16 (transposed)
//   CTX @41943040 [4096][1024] bf16
// MFMA 16x16x32_bf16 frags: A[m=lane&15][k=quad*8+i], B[n=lane&15][k=quad*8+i],
// C/D[row=quad*4+reg][col=lane&15]. Swapped operands -> D = C^T.

typedef __attribute__((ext_vector_type(8))) short bf16x8;
typedef __attribute__((ext_vector_type(4))) float f32x4;

#define LOG2E 1.44269504f

#define MFMA16(a, b, c) __builtin_amdgcn_mfma_f32_16x16x32_bf16((a), (b), (c), 0, 0, 0)

#define GLDS16(g, s)                                                        \
  __builtin_amdgcn_global_load_lds(                                         \
      (const __attribute__((address_space(1))) void*)(g),                   \
      (__attribute__((address_space(3))) void*)(s), 16, 0, 0)

// Manual barrier: wait until <= N vector-memory ops outstanding, then barrier.
// ONLY valid when the loop's vmem traffic is exclusively the staged GLDS.
#define ASYNC_BAR(N) asm volatile("s_waitcnt vmcnt(" #N ")\n\ts_barrier" ::: "memory")

#if __has_builtin(__builtin_amdgcn_exp2f)
#define EXP2F(x) __builtin_amdgcn_exp2f(x)
#else
#define EXP2F(x) exp2f(x)
#endif

static __device__ __forceinline__ unsigned short f2bf(float f) {  // RNE
  unsigned int u = __builtin_bit_cast(unsigned int, f);
  u += 0x7FFFu + ((u >> 16) & 1u);
  return (unsigned short)(u >> 16);
}

// pack two fp32 -> two bf16 (round-nearest) in one u32: 2 add + 1 perm
static __device__ __forceinline__ unsigned int pk2bf(float a, float b) {
  const unsigned int ua = __builtin_bit_cast(unsigned int, a) + 0x8000u;
  const unsigned int ub = __builtin_bit_cast(unsigned int, b) + 0x8000u;
  return __builtin_amdgcn_perm(ub, ua, 0x07060302);
}

// ---------------------------------------------------------------------------
__global__ __launch_bounds__(256) void cast_bf16(const float* __restrict__ x,
                                                 const float* __restrict__ wq,
                                                 const float* __restrict__ wo,
                                                 unsigned short* __restrict__ xb,
                                                 unsigned short* __restrict__ wqb,
                                                 unsigned short* __restrict__ wob)
{
  const int id = blockIdx.x * 256 + threadIdx.x;
  const float* src;
  unsigned short* dst;
  int off;
  if (id < 1048576)               { src = x;  dst = xb;  off = id; }
  else if (id < 1048576 + 786432) { src = wq; dst = wqb; off = id - 1048576; }
  else                            { src = wo; dst = wob; off = id - (1048576 + 786432); }
  float4 v = ((const float4*)src)[off];
  ushort4 o;
  o.x = f2bf(v.x); o.y = f2bf(v.y); o.z = f2bf(v.z); o.w = f2bf(v.w);
  ((ushort4*)dst)[off] = o;
}

// ---------------------------------------------------------------------------
// MFMA GEMM, TRIPLE-buffered K-loop, manual barriers (prefetch distance 2).
// Unchanged from R9 (validated: ~6-7 us win over dbuf+__syncthreads).
// ---------------------------------------------------------------------------
template <int MODE>
__global__ __launch_bounds__(256) void gemm_bt(const unsigned short* __restrict__ A,
                                               const unsigned short* __restrict__ B,
                                               const float* __restrict__ bias,
                                               float* __restrict__ OutF,
                                               unsigned short* __restrict__ Qb,
                                               unsigned short* __restrict__ Kb,
                                               unsigned short* __restrict__ Vt)
{
  __shared__ unsigned short pool[24576];   // 3 stages x (A 4096 | B 4096) shorts

  const int tid  = threadIdx.x;
  const int wave = tid >> 6, lane = tid & 63, quad = lane >> 4, cl = lane & 15;
  const int wm = wave >> 1, wn = wave & 1;
  const int m0 = blockIdx.y * 128, n0 = blockIdx.x * 128;
  const int sr = lane >> 2, sc = lane & 3;

  const int part = (MODE == 1) ? (n0 >> 10) : 0;     // 0=Q 1=K 2=V
  const bool swapped = (MODE == 0) || (part < 2);

  f32x4 acc[4][4];
  #pragma unroll
  for (int i = 0; i < 4; ++i)
    #pragma unroll
    for (int j = 0; j < 4; ++j)
      #pragma unroll
      for (int r = 0; r < 4; ++r) acc[i][j][r] = 0.f;

  const int scs = (sc ^ ((sr >> 1) & 3)) * 8;
  const int rchunk = (quad ^ ((cl >> 1) & 3)) * 8;

  auto stage = [&](int k0, int buf) {
    unsigned short* As = pool + buf * 8192;
    unsigned short* Bs = As + 4096;
    #pragma unroll
    for (int ii = 0; ii < 2; ++ii) {
      const int r = wave * 32 + ii * 16 + sr;
      GLDS16(A + (size_t)(m0 + r) * 1024 + k0 + scs, &As[(wave * 32 + ii * 16) * 32]);
      GLDS16(B + (size_t)(n0 + r) * 1024 + k0 + scs, &Bs[(wave * 32 + ii * 16) * 32]);
    }
  };

  stage(0, 0);
  stage(32, 1);
  int cur = 0;
  #pragma unroll 1
  for (int it = 0; it < 32; ++it) {
    if (it + 2 < 32) {
      ASYNC_BAR(4);                              // drain stage(it); keep stage(it+1)
      const int bnx = (cur == 0) ? 2 : cur - 1;  // (cur+2)%3
      stage((it + 2) * 32, bnx);
    } else if (it + 1 < 32) {
      ASYNC_BAR(4);
    } else {
      ASYNC_BAR(0);
    }

    const unsigned short* As = pool + cur * 8192;
    const unsigned short* Bs = As + 4096;
    bf16x8 af[4], bfr[4];
    #pragma unroll
    for (int mt = 0; mt < 4; ++mt)
      af[mt] = *(const bf16x8*)&As[(wm * 64 + mt * 16 + cl) * 32 + rchunk];
    #pragma unroll
    for (int nt = 0; nt < 4; ++nt)
      bfr[nt] = *(const bf16x8*)&Bs[(wn * 64 + nt * 16 + cl) * 32 + rchunk];

    if (swapped) {
      #pragma unroll
      for (int mt = 0; mt < 4; ++mt)
        #pragma unroll
        for (int nt = 0; nt < 4; ++nt)
          acc[mt][nt] = MFMA16(bfr[nt], af[mt], acc[mt][nt]);   // D = C^T
    } else {
      #pragma unroll
      for (int mt = 0; mt < 4; ++mt)
        #pragma unroll
        for (int nt = 0; nt < 4; ++nt)
          acc[mt][nt] = MFMA16(af[mt], bfr[nt], acc[mt][nt]);
    }
    cur = (cur == 2) ? 0 : cur + 1;
  }

  if (MODE == 1) {
    const int bb = m0 >> 11, ss = m0 & 2047;
    if (part == 2) {
      // V (normal orientation): transpose through LDS, coalesced Vt row stores
      #pragma unroll
      for (int half = 0; half < 2; ++half) {
        __syncthreads();
        if (wn == half) {
          #pragma unroll
          for (int mt = 0; mt < 4; ++mt)
            #pragma unroll
            for (int nt = 0; nt < 4; ++nt) {
              const int nl = nt * 16 + cl;
              const int ml = wm * 64 + mt * 16 + quad * 4;
              ushort4 pk;
              pk.x = f2bf(acc[mt][nt][0]); pk.y = f2bf(acc[mt][nt][1]);
              pk.z = f2bf(acc[mt][nt][2]); pk.w = f2bf(acc[mt][nt][3]);
              *(ushort4*)&pool[nl * 136 + ml] = pk;
            }
        }
        __syncthreads();
        const int row = tid >> 2, q4 = tid & 3;
        const int nglob = n0 + half * 64 + row;
        const int hh = (nglob >> 6) & 15, d = nglob & 63;
        unsigned short* drow = Vt + ((size_t)(bb * 16 + hh) * 64 + d) * 2048 + ss;
        #pragma unroll
        for (int i = 0; i < 4; ++i) {
          const bf16x8 v = *(const bf16x8*)&pool[row * 136 + q4 * 32 + i * 8];
          *(bf16x8*)(drow + q4 * 32 + i * 8) = v;
        }
      }
    } else {
      // Q/K (swapped: D=C^T): lane holds 4 consecutive d for one s -> ushort4
      unsigned short* dst = (part == 0) ? Qb : Kb;
      const float sc2 = (part == 0) ? LOG2E : 1.0f;
      #pragma unroll
      for (int mt = 0; mt < 4; ++mt) {
        const int m = ss + wm * 64 + mt * 16 + cl;
        #pragma unroll
        for (int nt = 0; nt < 4; ++nt) {
          const int np = (n0 & 1023) + wn * 64 + nt * 16 + quad * 4;
          const int hh = np >> 6, d0 = np & 63;
          ushort4 pk;
          pk.x = f2bf(acc[mt][nt][0] * sc2);
          pk.y = f2bf(acc[mt][nt][1] * sc2);
          pk.z = f2bf(acc[mt][nt][2] * sc2);
          pk.w = f2bf(acc[mt][nt][3] * sc2);
          *(ushort4*)&dst[((size_t)(bb * 16 + hh) * 2048 + m) * 64 + d0] = pk;
        }
      }
    }
  } else {
    #pragma unroll
    for (int mt = 0; mt < 4; ++mt) {
      const int m = m0 + wm * 64 + mt * 16 + cl;
      #pragma unroll
      for (int nt = 0; nt < 4; ++nt) {
        const int n = n0 + wn * 64 + nt * 16 + quad * 4;
        const float4 bv = *(const float4*)(bias + n);
        float4 o;
        o.x = acc[mt][nt][0] + bv.x; o.y = acc[mt][nt][1] + bv.y;
        o.z = acc[mt][nt][2] + bv.z; o.w = acc[mt][nt][3] + bv.w;
        *(float4*)&OutF[(size_t)m * 1024 + n] = o;
      }
    }
  }
}

// ---------------------------------------------------------------------------
// Flash attention R10: R8 structure (K AND V staged in LDS via GLDS) with
// triple-buffered staging + manual vmcnt(4) barriers. Loop vmem = staging
// GLDS only -> vmcnt accounting exact. Uniform blocks (wave owns low group g
// and high 127-g); no-max softmax P = 2^(q·k·log2e); per-wave P LDS.
// ---------------------------------------------------------------------------
__global__ __launch_bounds__(256) void attn_mfma(const unsigned short* __restrict__ Qb,
                                                 const unsigned short* __restrict__ Kb,
                                                 const unsigned short* __restrict__ Vt,
                                                 unsigned short* __restrict__ CTX)
{
  __shared__ unsigned short Ksm[3][64 * 64];
  __shared__ unsigned short Vsm[3][64 * 64];
  __shared__ unsigned short Psm[4][32 * 40];

  const int tid  = threadIdx.x;
  const int wave = tid >> 6, lane = tid & 63, quad = lane >> 4, cl = lane & 15;

  const int L  = blockIdx.x;
  const int bh = 4 * (L & 7) + ((L >> 3) & 3);    // XCD-affine: 4 bh per XCD
  const int b  = bh >> 4, h = bh & 15;
  const int p  = L >> 5;                          // 0..15
  const int g  = p * 4 + wave;                    // low group 0..63
  const int qlo = g * 16;
  const int qhi = (127 - g) * 16;
  const size_t base = (size_t)bh * (2048 * 64);

  bf16x8 qf[2][2];
  #pragma unroll
  for (int dk = 0; dk < 2; ++dk) {
    qf[0][dk] = *(const bf16x8*)(Qb + base + (size_t)(qlo + cl) * 64 + dk * 32 + quad * 8);
    qf[1][dk] = *(const bf16x8*)(Qb + base + (size_t)(qhi + cl) * 64 + dk * 32 + quad * 8);
  }

  f32x4 oacc[2][4];
  #pragma unroll
  for (int mf = 0; mf < 2; ++mf)
    #pragma unroll
    for (int dt = 0; dt < 4; ++dt)
      #pragma unroll
      for (int r = 0; r < 4; ++r) oacc[mf][dt][r] = 0.f;
  float lr[2][4] = {};

  bf16x8 ones;
  #pragma unroll
  for (int k = 0; k < 8; ++k) ones[k] = (short)0x3F80;

  const int lrow  = lane >> 3;
  const int lslot = (lane & 7) ^ lrow;
  const int nch = 32 - p;                          // >= 17

  auto stageKV = [&](int j64, int buf) {
    #pragma unroll
    for (int ii = 0; ii < 2; ++ii) {
      const int r0 = wave * 16 + ii * 8;
      GLDS16(Kb + base + (size_t)(j64 + r0 + lrow) * 64 + lslot * 8, &Ksm[buf][r0 * 64]);
      GLDS16(Vt + base + (size_t)(r0 + lrow) * 2048 + j64 + lslot * 8, &Vsm[buf][r0 * 64]);
    }
  };

  stageKV(0, 0);
  stageKV(64, 1);
  int cur = 0;
  #pragma unroll 1
  for (int ch = 0; ch < nch; ++ch) {
    if (ch + 2 < nch) {
      ASYNC_BAR(4);                              // drain stage(ch); keep stage(ch+1)
      const int bnx = (cur == 0) ? 2 : cur - 1;
      stageKV((ch + 2) * 64, bnx);
    } else if (ch + 1 < nch) {
      ASYNC_BAR(4);
    } else {
      ASYNC_BAR(0);
    }

    const int j64 = ch * 64;
    #pragma unroll
    for (int jli = 0; jli < 2; ++jli) {
      const int jg0 = j64 + jli * 32;
      if (jg0 > qhi + 15) continue;
      const bool lowAct = (jg0 <= qlo + 15);
      const int jl = jli * 32;

      bf16x8 kf[2][2];
      #pragma unroll
      for (int jf = 0; jf < 2; ++jf)
        #pragma unroll
        for (int dk = 0; dk < 2; ++dk) {
          const int jrow = jl + jf * 16 + cl;
          const int slot = (dk * 4 + quad) ^ (cl & 7);
          kf[jf][dk] = *(const bf16x8*)&Ksm[cur][jrow * 64 + slot * 8];
        }

      f32x4 st[2][2];
      #pragma unroll
      for (int jf = 0; jf < 2; ++jf)
        #pragma unroll
        for (int mf = 0; mf < 2; ++mf) {
          if (mf == 0 && !lowAct) continue;
          f32x4 z;
          #pragma unroll
          for (int r = 0; r < 4; ++r) z[r] = 0.f;
          z = MFMA16(kf[jf][0], qf[mf][0], z);
          st[jf][mf] = MFMA16(kf[jf][1], qf[mf][1], z);
        }

      #pragma unroll
      for (int mf = 0; mf < 2; ++mf) {
        if (mf == 0 && !lowAct) continue;
        const int qbase = mf ? qhi : qlo;
        const bool diag = (jg0 + 32 > qbase);
        #pragma unroll
        for (int jf = 0; jf < 2; ++jf) {
          float pv[4];
          if (diag) {
            const int qg = qbase + cl;
            #pragma unroll
            for (int r = 0; r < 4; ++r) {
              const int jg = jg0 + jf * 16 + quad * 4 + r;
              pv[r] = (jg <= qg) ? EXP2F(st[jf][mf][r]) : 0.f;
            }
          } else {
            #pragma unroll
            for (int r = 0; r < 4; ++r) pv[r] = EXP2F(st[jf][mf][r]);
          }
          uint2 w;
          w.x = pk2bf(pv[0], pv[1]);
          w.y = pk2bf(pv[2], pv[3]);
          *(uint2*)&Psm[wave][(mf * 16 + cl) * 40 + jf * 16 + quad * 4] = w;
        }
      }

      bf16x8 vf[4];
      #pragma unroll
      for (int dt = 0; dt < 4; ++dt) {
        const int d = dt * 16 + cl;
        const int slot = ((jl >> 3) + quad) ^ (cl & 7);
        vf[dt] = *(const bf16x8*)&Vsm[cur][d * 64 + slot * 8];
      }

      #pragma unroll
      for (int mf = 0; mf < 2; ++mf) {
        if (mf == 0 && !lowAct) continue;
        const bf16x8 pf = *(const bf16x8*)&Psm[wave][(mf * 16 + cl) * 40 + quad * 8];
        f32x4 z;
        #pragma unroll
        for (int r = 0; r < 4; ++r) z[r] = 0.f;
        const f32x4 ls = MFMA16(pf, ones, z);
        #pragma unroll
        for (int r = 0; r < 4; ++r) lr[mf][r] += ls[r];
        #pragma unroll
        for (int dt = 0; dt < 4; ++dt)
          oacc[mf][dt] = MFMA16(pf, vf[dt], oacc[mf][dt]);
      }
    }
    cur = (cur == 2) ? 0 : cur + 1;
  }

  #pragma unroll
  for (int mf = 0; mf < 2; ++mf) {
    const int qbase = mf ? qhi : qlo;
    float inv[4];
    #pragma unroll
    for (int r = 0; r < 4; ++r) inv[r] = 1.f / lr[mf][r];
    #pragma unroll
    for (int dt = 0; dt < 4; ++dt)
      #pragma unroll
      for (int r = 0; r < 4; ++r)
        CTX[(size_t)(b * 2048 + qbase + quad * 4 + r) * 1024 +
            h * 64 + dt * 16 + cl] = f2bf(oacc[mf][dt][r] * inv[r]);
  }
}

// ---------------------------------------------------------------------------
extern "C" void kernel_launch(void* const* d_in, const int* in_sizes, int n_in,
                              void* d_out, int out_size, void* d_ws, size_t ws_size,
                              hipStream_t stream)
{
  const float* x    = (const float*)d_in[0];
  const float* Wqkv = (const float*)d_in[1];
  const float* Wout = (const float*)d_in[2];
  const float* bout = (const float*)d_in[3];
  float* out = (float*)d_out;

  char* ws = (char*)d_ws;
  unsigned short* xb  = (unsigned short*)(ws);
  unsigned short* wqb = (unsigned short*)(ws + 8388608);
  unsigned short* wob = (unsigned short*)(ws + 14680064);
  unsigned short* Qb  = (unsigned short*)(ws + 16777216);
  unsigned short* Kb  = (unsigned short*)(ws + 25165824);
  unsigned short* Vt  = (unsigned short*)(ws + 33554432);
  unsigned short* CTX = (unsigned short*)(ws + 41943040);

  cast_bf16<<<dim3(8192), dim3(256), 0, stream>>>(x, Wqkv, Wout, xb, wqb, wob);

  // QKV projection: M=4096, N=3072, K=1024
  gemm_bt<1><<<dim3(24, 32), dim3(256), 0, stream>>>(xb, wqb, nullptr, nullptr, Qb, Kb, Vt);

  // Flash attention: 512 uniform blocks (XCD-affine bh), 4 waves each
  attn_mfma<<<dim3(512), dim3(256), 0, stream>>>(Qb, Kb, Vt, CTX);

  // Output projection: M=4096, N=1024, K=1024, + bias
  gemm_bt<0><<<dim3(8, 32), dim3(256), 0, stream>>>(CTX, wob, bout, out, nullptr, nullptr, nullptr);
}